// Round 1
// baseline (329.786 us; speedup 1.0000x reference)
//
#include <hip/hip_runtime.h>
#include <hip/hip_bf16.h>

// WindowAttention3D: 3136 windows, N=64 tokens, C=128, H=4 heads, hd=32.
// One block per window, 4 waves, wave = head.
// v2: swapped-S^T attention (lane owns q-row), MFMA ones-row row-sum, no
// max-subtraction, per-mt double-buffered K/Q staging, O staged in dead xs
// at stride 136 (aligned b128). LDS 27648 B -> 5 blocks/CU.
//
// LDS map (bf16 elements):
//   [0, 8704)        xs  [64][136]  x staging -- later O staging [64][136]
//   [8704, 13824)    per-wave buf 1280 el:
//                      K/Q: 2 slots of [16][40] (double-buffered per mt)
//                      V:   [32][40] per token-half
//                      P:   [16][72] (0..1151) + ones row (1152..1215)

typedef __bf16 bf16x8 __attribute__((ext_vector_type(8)));
typedef __bf16 bf16x4 __attribute__((ext_vector_type(4)));
typedef float f32x4 __attribute__((ext_vector_type(4)));

#define NWMASK 392
#define SCALE 0.17677669529663687f  // 1/sqrt(32)

// ---------------- prep: weights->bf16, rpe gather ----------------
__global__ void prep(const float* __restrict__ qkv_w, const float* __restrict__ proj_w,
                     const float* __restrict__ tbl, const int* __restrict__ ridx,
                     __bf16* __restrict__ wqkv, __bf16* __restrict__ wproj,
                     float* __restrict__ rpe) {
    int i = blockIdx.x * 256 + threadIdx.x;          // 81920 threads
    if (i < 49152) {
        wqkv[i] = (__bf16)qkv_w[i];                  // [384][128]
    } else if (i < 65536) {
        int j = i - 49152;  wproj[j] = (__bf16)proj_w[j];   // [128][128]
    } else {
        int j = i - 65536;                           // rpe [4][64][64]
        rpe[j] = tbl[ridx[j & 4095] * 4 + (j >> 12)];
    }
}

// ---------------- main fused kernel ----------------
__global__ __launch_bounds__(256, 5) void wattn_main(
    const float* __restrict__ x, const float* __restrict__ mask,
    const float* __restrict__ qkv_b, const float* __restrict__ proj_b,
    const __bf16* __restrict__ wqkv, const __bf16* __restrict__ wproj,
    const float* __restrict__ rpe, float* __restrict__ out)
{
    __shared__ __align__(16) __bf16 smem[13824];   // 27648 B
    const int win  = blockIdx.x;
    const int tid  = threadIdx.x;
    const int h    = tid >> 6;        // wave id = head
    const int lane = tid & 63;
    const int quad = lane >> 4;
    const int l16  = lane & 15;

    __bf16* const xs  = smem;                     // [64][136]; O staging later
    __bf16* const buf = smem + 8704 + h * 1280;   // wave-private

    // ---- Phase 0: cooperative x staging, fp32 -> bf16, fully coalesced ----
    {
        const float* xb = x + (size_t)win * 8192;
        #pragma unroll
        for (int i = 0; i < 2; ++i) {
            const int row  = h * 16 + (lane >> 3) + i * 8;
            const int colg = (lane & 7) * 16;
            const float* xp = xb + row * 128 + colg;
            float4 a0 = *(const float4*)(xp);
            float4 a1 = *(const float4*)(xp + 4);
            float4 a2 = *(const float4*)(xp + 8);
            float4 a3 = *(const float4*)(xp + 12);
            bf16x8 t0, t1;
            t0[0]=(__bf16)a0.x; t0[1]=(__bf16)a0.y; t0[2]=(__bf16)a0.z; t0[3]=(__bf16)a0.w;
            t0[4]=(__bf16)a1.x; t0[5]=(__bf16)a1.y; t0[6]=(__bf16)a1.z; t0[7]=(__bf16)a1.w;
            t1[0]=(__bf16)a2.x; t1[1]=(__bf16)a2.y; t1[2]=(__bf16)a2.z; t1[3]=(__bf16)a2.w;
            t1[4]=(__bf16)a3.x; t1[5]=(__bf16)a3.y; t1[6]=(__bf16)a3.z; t1[7]=(__bf16)a3.w;
            *(bf16x8*)(xs + row * 136 + colg)     = t0;
            *(bf16x8*)(xs + row * 136 + colg + 8) = t1;
        }
    }
    __syncthreads();   // barrier 1: xs ready

    bf16x8 kf[4], qf[4], vf[2][2];

    // ---- K phase: feats 128+h*32+[0,32) -> per-mt stage [16][40] (dbuf) ----
    {
        bf16x8 wf[2][4]; float bb[2];
        #pragma unroll
        for (int nt = 0; nt < 2; ++nt) {
            const int ng = 128 + h * 32 + nt * 16 + l16;
            bb[nt] = qkv_b[ng];
            #pragma unroll
            for (int kt = 0; kt < 4; ++kt)
                wf[nt][kt] = *(const bf16x8*)(wqkv + ng * 128 + kt * 32 + quad * 8);
        }
        #pragma unroll
        for (int mt = 0; mt < 4; ++mt) {
            __bf16* const sb = buf + (mt & 1) * 640;
            bf16x8 af[4];
            #pragma unroll
            for (int kt = 0; kt < 4; ++kt)
                af[kt] = *(const bf16x8*)(xs + (mt * 16 + l16) * 136 + kt * 32 + quad * 8);
            #pragma unroll
            for (int nt = 0; nt < 2; ++nt) {
                f32x4 acc = {0.f, 0.f, 0.f, 0.f};
                #pragma unroll
                for (int kt = 0; kt < 4; ++kt)
                    acc = __builtin_amdgcn_mfma_f32_16x16x32_bf16(af[kt], wf[nt][kt], acc, 0, 0, 0);
                #pragma unroll
                for (int r = 0; r < 4; ++r)
                    sb[(quad * 4 + r) * 40 + nt * 16 + l16] = (__bf16)(acc[r] + bb[nt]);
            }
            kf[mt] = *(const bf16x8*)(sb + l16 * 40 + quad * 8);
        }
    }

    // ---- Q phase: feats h*32+[0,32), pre-scaled -> qf ----
    {
        bf16x8 wf[2][4]; float bb[2];
        #pragma unroll
        for (int nt = 0; nt < 2; ++nt) {
            const int ng = h * 32 + nt * 16 + l16;
            bb[nt] = qkv_b[ng];
            #pragma unroll
            for (int kt = 0; kt < 4; ++kt)
                wf[nt][kt] = *(const bf16x8*)(wqkv + ng * 128 + kt * 32 + quad * 8);
        }
        #pragma unroll
        for (int mt = 0; mt < 4; ++mt) {
            __bf16* const sb = buf + (mt & 1) * 640;
            bf16x8 af[4];
            #pragma unroll
            for (int kt = 0; kt < 4; ++kt)
                af[kt] = *(const bf16x8*)(xs + (mt * 16 + l16) * 136 + kt * 32 + quad * 8);
            #pragma unroll
            for (int nt = 0; nt < 2; ++nt) {
                f32x4 acc = {0.f, 0.f, 0.f, 0.f};
                #pragma unroll
                for (int kt = 0; kt < 4; ++kt)
                    acc = __builtin_amdgcn_mfma_f32_16x16x32_bf16(af[kt], wf[nt][kt], acc, 0, 0, 0);
                #pragma unroll
                for (int r = 0; r < 4; ++r)
                    sb[(quad * 4 + r) * 40 + nt * 16 + l16] = (__bf16)((acc[r] + bb[nt]) * SCALE);
            }
            qf[mt] = *(const bf16x8*)(sb + l16 * 40 + quad * 8);
        }
    }

    // ---- V phase: feats 256+h*32+[0,32) -> V^T [32][40] per token-half ----
    {
        #pragma unroll
        for (int half = 0; half < 2; ++half) {
            #pragma unroll
            for (int m2 = 0; m2 < 2; ++m2) {
                const int mt = half * 2 + m2;
                bf16x8 af[4];
                #pragma unroll
                for (int kt = 0; kt < 4; ++kt)
                    af[kt] = *(const bf16x8*)(xs + (mt * 16 + l16) * 136 + kt * 32 + quad * 8);
                #pragma unroll
                for (int nt = 0; nt < 2; ++nt) {
                    const int ng = 256 + h * 32 + nt * 16 + l16;
                    const float bb = qkv_b[ng];
                    bf16x8 w0 = *(const bf16x8*)(wqkv + ng * 128 +       quad * 8);
                    bf16x8 w1 = *(const bf16x8*)(wqkv + ng * 128 +  32 + quad * 8);
                    bf16x8 w2 = *(const bf16x8*)(wqkv + ng * 128 +  64 + quad * 8);
                    bf16x8 w3 = *(const bf16x8*)(wqkv + ng * 128 +  96 + quad * 8);
                    f32x4 acc = {0.f, 0.f, 0.f, 0.f};
                    acc = __builtin_amdgcn_mfma_f32_16x16x32_bf16(af[0], w0, acc, 0, 0, 0);
                    acc = __builtin_amdgcn_mfma_f32_16x16x32_bf16(af[1], w1, acc, 0, 0, 0);
                    acc = __builtin_amdgcn_mfma_f32_16x16x32_bf16(af[2], w2, acc, 0, 0, 0);
                    acc = __builtin_amdgcn_mfma_f32_16x16x32_bf16(af[3], w3, acc, 0, 0, 0);
                    bf16x4 pk;
                    #pragma unroll
                    for (int r = 0; r < 4; ++r) pk[r] = (__bf16)(acc[r] + bb);
                    *(bf16x4*)(buf + (nt * 16 + l16) * 40 + m2 * 16 + quad * 4) = pk;
                }
            }
            #pragma unroll
            for (int nf = 0; nf < 2; ++nf)
                vf[half][nf] = *(const bf16x8*)(buf + (nf * 16 + l16) * 40 + quad * 8);
        }
        buf[1152 + lane] = (__bf16)1.0f;   // ones row for MFMA row-sum
    }
    __syncthreads();   // barrier 2: all xs reads done -> O staging overlay safe

    // ---- attention: S^T = mfma(K,Q) so lane owns a full q-row; exp w/o
    //      max-sub; row-sum via ones-row MFMA; P packed b64 -> PV ----
    const float* rh = rpe + h * 4096;
    const float* mw = mask + (size_t)(win % NWMASK) * 4096;
    #pragma unroll
    for (int jb = 0; jb < 4; ++jb) {
        const int qrow = jb * 16 + l16;
        f32x4 st[4];
        #pragma unroll
        for (int it = 0; it < 4; ++it) {
            f32x4 z = {0.f, 0.f, 0.f, 0.f};
            st[it] = __builtin_amdgcn_mfma_f32_16x16x32_bf16(kf[it], qf[jb], z, 0, 0, 0);
        }
        #pragma unroll
        for (int it = 0; it < 4; ++it) {
            float4 r4 = *(const float4*)(rh + qrow * 64 + it * 16 + quad * 4);
            float4 m4 = *(const float4*)(mw + qrow * 64 + it * 16 + quad * 4);
            bf16x4 pk;
            pk[0] = (__bf16)__expf(st[it][0] + r4.x + m4.x);
            pk[1] = (__bf16)__expf(st[it][1] + r4.y + m4.y);
            pk[2] = (__bf16)__expf(st[it][2] + r4.z + m4.z);
            pk[3] = (__bf16)__expf(st[it][3] + r4.w + m4.w);
            *(bf16x4*)(buf + l16 * 72 + it * 16 + quad * 4) = pk;
        }
        f32x4 oa[2] = {{0.f,0.f,0.f,0.f},{0.f,0.f,0.f,0.f}};
        f32x4 os = {0.f, 0.f, 0.f, 0.f};
        #pragma unroll
        for (int kt = 0; kt < 2; ++kt) {
            bf16x8 pf = *(const bf16x8*)(buf + l16 * 72 + kt * 32 + quad * 8);
            bf16x8 o1 = *(const bf16x8*)(buf + 1152 + kt * 32 + quad * 8);  // broadcast
            oa[0] = __builtin_amdgcn_mfma_f32_16x16x32_bf16(pf, vf[kt][0], oa[0], 0, 0, 0);
            oa[1] = __builtin_amdgcn_mfma_f32_16x16x32_bf16(pf, vf[kt][1], oa[1], 0, 0, 0);
            os    = __builtin_amdgcn_mfma_f32_16x16x32_bf16(pf, o1, os, 0, 0, 0);
        }
        #pragma unroll
        for (int r = 0; r < 4; ++r) {
            const float inv = 1.0f / os[r];
            const int orow = jb * 16 + quad * 4 + r;
            xs[orow * 136 + h * 32 + l16]      = (__bf16)(oa[0][r] * inv);
            xs[orow * 136 + h * 32 + 16 + l16] = (__bf16)(oa[1][r] * inv);
        }
    }
    __syncthreads();   // barrier 3: O staging (all heads) ready

    // ---- proj GEMM: wave h = token band, K=128 over 4 heads' O ----
    bf16x8 of[4];
    #pragma unroll
    for (int kt = 0; kt < 4; ++kt)
        of[kt] = *(const bf16x8*)(xs + (h * 16 + l16) * 136 + kt * 32 + quad * 8);
    #pragma unroll
    for (int nt = 0; nt < 8; ++nt) {
        const int ng = nt * 16 + l16;
        const float b = proj_b[ng];
        bf16x8 wf[4];
        #pragma unroll
        for (int kt = 0; kt < 4; ++kt)
            wf[kt] = *(const bf16x8*)(wproj + ng * 128 + kt * 32 + quad * 8);
        f32x4 acc = {0.f, 0.f, 0.f, 0.f};
        #pragma unroll
        for (int kt = 0; kt < 4; ++kt)
            acc = __builtin_amdgcn_mfma_f32_16x16x32_bf16(of[kt], wf[kt], acc, 0, 0, 0);
        float* dst = out + ((size_t)win * 64 + h * 16 + quad * 4) * 128 + ng;
        #pragma unroll
        for (int r = 0; r < 4; ++r) dst[(size_t)r * 128] = acc[r] + b;
    }
}

// ---------------- launch ----------------
extern "C" void kernel_launch(void* const* d_in, const int* in_sizes, int n_in,
                              void* d_out, int out_size, void* d_ws, size_t ws_size,
                              hipStream_t stream) {
    const float* x      = (const float*)d_in[0];
    const float* mask   = (const float*)d_in[1];
    const float* qkv_w  = (const float*)d_in[2];
    const float* qkv_b  = (const float*)d_in[3];
    const float* proj_w = (const float*)d_in[4];
    const float* proj_b = (const float*)d_in[5];
    const float* tbl    = (const float*)d_in[6];
    const int*   ridx   = (const int*)d_in[7];
    float* out = (float*)d_out;

    // ws: wqkv bf16 [384*128] | wproj bf16 [128*128] | rpe f32 [4*64*64]
    __bf16* wqkv  = (__bf16*)d_ws;
    __bf16* wproj = wqkv + 384 * 128;
    float*  rpe   = (float*)((char*)d_ws + 131072);

    prep<<<320, 256, 0, stream>>>(qkv_w, proj_w, tbl, ridx, wqkv, wproj, rpe);
    wattn_main<<<3136, 256, 0, stream>>>(x, mask, qkv_b, proj_b, wqkv, wproj, rpe, out);
}

// Round 2
// 308.244 us; speedup vs baseline: 1.0699x; 1.0699x over previous
//
#include <hip/hip_runtime.h>
#include <hip/hip_bf16.h>

// WindowAttention3D: 3136 windows, N=64 tokens, C=128, H=4 heads, hd=32.
// One block per window, 4 waves, wave = head.
// v3: v2 structure (swapped-S^T attention, MFMA ones-row row-sum, no max-sub,
// per-mt double-buffered K/Q staging, O staged in dead xs) with the
// register-clamp bug reverted: launch_bounds(256,4) (v2's (256,5) forced
// VGPR=48 -> ~120 MB scratch spill traffic). Ones fragment now a register
// constant (no LDS row); rpe/mask loads hoisted above the S^T MFMAs.
// LDS 27648 B -> 5 blocks/CU reachable if VGPR <= 102.
//
// LDS map (bf16 elements):
//   [0, 8704)        xs  [64][136]  x staging -- later O staging [64][136]
//   [8704, 13824)    per-wave buf 1280 el:
//                      K/Q: 2 slots of [16][40] (double-buffered per mt)
//                      V:   [32][40] per token-half
//                      P:   [16][72]

typedef __bf16 bf16x8 __attribute__((ext_vector_type(8)));
typedef __bf16 bf16x4 __attribute__((ext_vector_type(4)));
typedef float f32x4 __attribute__((ext_vector_type(4)));

#define NWMASK 392
#define SCALE 0.17677669529663687f  // 1/sqrt(32)

// ---------------- prep: weights->bf16, rpe gather ----------------
__global__ void prep(const float* __restrict__ qkv_w, const float* __restrict__ proj_w,
                     const float* __restrict__ tbl, const int* __restrict__ ridx,
                     __bf16* __restrict__ wqkv, __bf16* __restrict__ wproj,
                     float* __restrict__ rpe) {
    int i = blockIdx.x * 256 + threadIdx.x;          // 81920 threads
    if (i < 49152) {
        wqkv[i] = (__bf16)qkv_w[i];                  // [384][128]
    } else if (i < 65536) {
        int j = i - 49152;  wproj[j] = (__bf16)proj_w[j];   // [128][128]
    } else {
        int j = i - 65536;                           // rpe [4][64][64]
        rpe[j] = tbl[ridx[j & 4095] * 4 + (j >> 12)];
    }
}

// ---------------- main fused kernel ----------------
__global__ __launch_bounds__(256, 4) void wattn_main(
    const float* __restrict__ x, const float* __restrict__ mask,
    const float* __restrict__ qkv_b, const float* __restrict__ proj_b,
    const __bf16* __restrict__ wqkv, const __bf16* __restrict__ wproj,
    const float* __restrict__ rpe, float* __restrict__ out)
{
    __shared__ __align__(16) __bf16 smem[13824];   // 27648 B
    const int win  = blockIdx.x;
    const int tid  = threadIdx.x;
    const int h    = tid >> 6;        // wave id = head
    const int lane = tid & 63;
    const int quad = lane >> 4;
    const int l16  = lane & 15;

    __bf16* const xs  = smem;                     // [64][136]; O staging later
    __bf16* const buf = smem + 8704 + h * 1280;   // wave-private

    // ---- Phase 0: cooperative x staging, fp32 -> bf16, fully coalesced ----
    {
        const float* xb = x + (size_t)win * 8192;
        #pragma unroll
        for (int i = 0; i < 2; ++i) {
            const int row  = h * 16 + (lane >> 3) + i * 8;
            const int colg = (lane & 7) * 16;
            const float* xp = xb + row * 128 + colg;
            float4 a0 = *(const float4*)(xp);
            float4 a1 = *(const float4*)(xp + 4);
            float4 a2 = *(const float4*)(xp + 8);
            float4 a3 = *(const float4*)(xp + 12);
            bf16x8 t0, t1;
            t0[0]=(__bf16)a0.x; t0[1]=(__bf16)a0.y; t0[2]=(__bf16)a0.z; t0[3]=(__bf16)a0.w;
            t0[4]=(__bf16)a1.x; t0[5]=(__bf16)a1.y; t0[6]=(__bf16)a1.z; t0[7]=(__bf16)a1.w;
            t1[0]=(__bf16)a2.x; t1[1]=(__bf16)a2.y; t1[2]=(__bf16)a2.z; t1[3]=(__bf16)a2.w;
            t1[4]=(__bf16)a3.x; t1[5]=(__bf16)a3.y; t1[6]=(__bf16)a3.z; t1[7]=(__bf16)a3.w;
            *(bf16x8*)(xs + row * 136 + colg)     = t0;
            *(bf16x8*)(xs + row * 136 + colg + 8) = t1;
        }
    }
    __syncthreads();   // barrier 1: xs ready

    bf16x8 kf[4], qf[4], vf[2][2];

    // ---- K phase: feats 128+h*32+[0,32) -> per-mt stage [16][40] (dbuf) ----
    {
        bf16x8 wf[2][4]; float bb[2];
        #pragma unroll
        for (int nt = 0; nt < 2; ++nt) {
            const int ng = 128 + h * 32 + nt * 16 + l16;
            bb[nt] = qkv_b[ng];
            #pragma unroll
            for (int kt = 0; kt < 4; ++kt)
                wf[nt][kt] = *(const bf16x8*)(wqkv + ng * 128 + kt * 32 + quad * 8);
        }
        #pragma unroll
        for (int mt = 0; mt < 4; ++mt) {
            __bf16* const sb = buf + (mt & 1) * 640;
            bf16x8 af[4];
            #pragma unroll
            for (int kt = 0; kt < 4; ++kt)
                af[kt] = *(const bf16x8*)(xs + (mt * 16 + l16) * 136 + kt * 32 + quad * 8);
            #pragma unroll
            for (int nt = 0; nt < 2; ++nt) {
                f32x4 acc = {0.f, 0.f, 0.f, 0.f};
                #pragma unroll
                for (int kt = 0; kt < 4; ++kt)
                    acc = __builtin_amdgcn_mfma_f32_16x16x32_bf16(af[kt], wf[nt][kt], acc, 0, 0, 0);
                #pragma unroll
                for (int r = 0; r < 4; ++r)
                    sb[(quad * 4 + r) * 40 + nt * 16 + l16] = (__bf16)(acc[r] + bb[nt]);
            }
            kf[mt] = *(const bf16x8*)(sb + l16 * 40 + quad * 8);
        }
    }

    // ---- Q phase: feats h*32+[0,32), pre-scaled -> qf ----
    {
        bf16x8 wf[2][4]; float bb[2];
        #pragma unroll
        for (int nt = 0; nt < 2; ++nt) {
            const int ng = h * 32 + nt * 16 + l16;
            bb[nt] = qkv_b[ng];
            #pragma unroll
            for (int kt = 0; kt < 4; ++kt)
                wf[nt][kt] = *(const bf16x8*)(wqkv + ng * 128 + kt * 32 + quad * 8);
        }
        #pragma unroll
        for (int mt = 0; mt < 4; ++mt) {
            __bf16* const sb = buf + (mt & 1) * 640;
            bf16x8 af[4];
            #pragma unroll
            for (int kt = 0; kt < 4; ++kt)
                af[kt] = *(const bf16x8*)(xs + (mt * 16 + l16) * 136 + kt * 32 + quad * 8);
            #pragma unroll
            for (int nt = 0; nt < 2; ++nt) {
                f32x4 acc = {0.f, 0.f, 0.f, 0.f};
                #pragma unroll
                for (int kt = 0; kt < 4; ++kt)
                    acc = __builtin_amdgcn_mfma_f32_16x16x32_bf16(af[kt], wf[nt][kt], acc, 0, 0, 0);
                #pragma unroll
                for (int r = 0; r < 4; ++r)
                    sb[(quad * 4 + r) * 40 + nt * 16 + l16] = (__bf16)((acc[r] + bb[nt]) * SCALE);
            }
            qf[mt] = *(const bf16x8*)(sb + l16 * 40 + quad * 8);
        }
    }

    // ---- V phase: feats 256+h*32+[0,32) -> V^T [32][40] per token-half ----
    {
        #pragma unroll
        for (int half = 0; half < 2; ++half) {
            #pragma unroll
            for (int m2 = 0; m2 < 2; ++m2) {
                const int mt = half * 2 + m2;
                bf16x8 af[4];
                #pragma unroll
                for (int kt = 0; kt < 4; ++kt)
                    af[kt] = *(const bf16x8*)(xs + (mt * 16 + l16) * 136 + kt * 32 + quad * 8);
                #pragma unroll
                for (int nt = 0; nt < 2; ++nt) {
                    const int ng = 256 + h * 32 + nt * 16 + l16;
                    const float bb = qkv_b[ng];
                    bf16x8 w0 = *(const bf16x8*)(wqkv + ng * 128 +       quad * 8);
                    bf16x8 w1 = *(const bf16x8*)(wqkv + ng * 128 +  32 + quad * 8);
                    bf16x8 w2 = *(const bf16x8*)(wqkv + ng * 128 +  64 + quad * 8);
                    bf16x8 w3 = *(const bf16x8*)(wqkv + ng * 128 +  96 + quad * 8);
                    f32x4 acc = {0.f, 0.f, 0.f, 0.f};
                    acc = __builtin_amdgcn_mfma_f32_16x16x32_bf16(af[0], w0, acc, 0, 0, 0);
                    acc = __builtin_amdgcn_mfma_f32_16x16x32_bf16(af[1], w1, acc, 0, 0, 0);
                    acc = __builtin_amdgcn_mfma_f32_16x16x32_bf16(af[2], w2, acc, 0, 0, 0);
                    acc = __builtin_amdgcn_mfma_f32_16x16x32_bf16(af[3], w3, acc, 0, 0, 0);
                    bf16x4 pk;
                    #pragma unroll
                    for (int r = 0; r < 4; ++r) pk[r] = (__bf16)(acc[r] + bb);
                    *(bf16x4*)(buf + (nt * 16 + l16) * 40 + m2 * 16 + quad * 4) = pk;
                }
            }
            #pragma unroll
            for (int nf = 0; nf < 2; ++nf)
                vf[half][nf] = *(const bf16x8*)(buf + (nf * 16 + l16) * 40 + quad * 8);
        }
    }
    __syncthreads();   // barrier 2: all xs reads done -> O staging overlay safe

    // ---- attention: S^T = mfma(K,Q) so lane owns a full q-row; exp w/o
    //      max-sub; row-sum via constant ones B-fragment; P packed b64 -> PV ----
    bf16x8 onesf;
    #pragma unroll
    for (int j = 0; j < 8; ++j) onesf[j] = (__bf16)1.0f;

    const float* rh = rpe + h * 4096;
    const float* mw = mask + (size_t)(win % NWMASK) * 4096;
    #pragma unroll
    for (int jb = 0; jb < 4; ++jb) {
        const int qrow = jb * 16 + l16;
        // hoist bias loads above the MFMAs so L2 latency overlaps them
        float4 r4[4], m4[4];
        #pragma unroll
        for (int it = 0; it < 4; ++it) {
            r4[it] = *(const float4*)(rh + qrow * 64 + it * 16 + quad * 4);
            m4[it] = *(const float4*)(mw + qrow * 64 + it * 16 + quad * 4);
        }
        f32x4 st[4];
        #pragma unroll
        for (int it = 0; it < 4; ++it) {
            f32x4 z = {0.f, 0.f, 0.f, 0.f};
            st[it] = __builtin_amdgcn_mfma_f32_16x16x32_bf16(kf[it], qf[jb], z, 0, 0, 0);
        }
        #pragma unroll
        for (int it = 0; it < 4; ++it) {
            bf16x4 pk;
            pk[0] = (__bf16)__expf(st[it][0] + r4[it].x + m4[it].x);
            pk[1] = (__bf16)__expf(st[it][1] + r4[it].y + m4[it].y);
            pk[2] = (__bf16)__expf(st[it][2] + r4[it].z + m4[it].z);
            pk[3] = (__bf16)__expf(st[it][3] + r4[it].w + m4[it].w);
            *(bf16x4*)(buf + l16 * 72 + it * 16 + quad * 4) = pk;
        }
        f32x4 oa[2] = {{0.f,0.f,0.f,0.f},{0.f,0.f,0.f,0.f}};
        f32x4 os = {0.f, 0.f, 0.f, 0.f};
        #pragma unroll
        for (int kt = 0; kt < 2; ++kt) {
            bf16x8 pf = *(const bf16x8*)(buf + l16 * 72 + kt * 32 + quad * 8);
            oa[0] = __builtin_amdgcn_mfma_f32_16x16x32_bf16(pf, vf[kt][0], oa[0], 0, 0, 0);
            oa[1] = __builtin_amdgcn_mfma_f32_16x16x32_bf16(pf, vf[kt][1], oa[1], 0, 0, 0);
            os    = __builtin_amdgcn_mfma_f32_16x16x32_bf16(pf, onesf,     os,    0, 0, 0);
        }
        #pragma unroll
        for (int r = 0; r < 4; ++r) {
            const float inv = 1.0f / os[r];
            const int orow = jb * 16 + quad * 4 + r;
            xs[orow * 136 + h * 32 + l16]      = (__bf16)(oa[0][r] * inv);
            xs[orow * 136 + h * 32 + 16 + l16] = (__bf16)(oa[1][r] * inv);
        }
    }
    __syncthreads();   // barrier 3: O staging (all heads) ready

    // ---- proj GEMM: wave h = token band, K=128 over 4 heads' O ----
    bf16x8 of[4];
    #pragma unroll
    for (int kt = 0; kt < 4; ++kt)
        of[kt] = *(const bf16x8*)(xs + (h * 16 + l16) * 136 + kt * 32 + quad * 8);
    #pragma unroll
    for (int nt = 0; nt < 8; ++nt) {
        const int ng = nt * 16 + l16;
        const float b = proj_b[ng];
        bf16x8 wf[4];
        #pragma unroll
        for (int kt = 0; kt < 4; ++kt)
            wf[kt] = *(const bf16x8*)(wproj + ng * 128 + kt * 32 + quad * 8);
        f32x4 acc = {0.f, 0.f, 0.f, 0.f};
        #pragma unroll
        for (int kt = 0; kt < 4; ++kt)
            acc = __builtin_amdgcn_mfma_f32_16x16x32_bf16(of[kt], wf[kt], acc, 0, 0, 0);
        float* dst = out + ((size_t)win * 64 + h * 16 + quad * 4) * 128 + ng;
        #pragma unroll
        for (int r = 0; r < 4; ++r) dst[(size_t)r * 128] = acc[r] + b;
    }
}

// ---------------- launch ----------------
extern "C" void kernel_launch(void* const* d_in, const int* in_sizes, int n_in,
                              void* d_out, int out_size, void* d_ws, size_t ws_size,
                              hipStream_t stream) {
    const float* x      = (const float*)d_in[0];
    const float* mask   = (const float*)d_in[1];
    const float* qkv_w  = (const float*)d_in[2];
    const float* qkv_b  = (const float*)d_in[3];
    const float* proj_w = (const float*)d_in[4];
    const float* proj_b = (const float*)d_in[5];
    const float* tbl    = (const float*)d_in[6];
    const int*   ridx   = (const int*)d_in[7];
    float* out = (float*)d_out;

    // ws: wqkv bf16 [384*128] | wproj bf16 [128*128] | rpe f32 [4*64*64]
    __bf16* wqkv  = (__bf16*)d_ws;
    __bf16* wproj = wqkv + 384 * 128;
    float*  rpe   = (float*)((char*)d_ws + 131072);

    prep<<<320, 256, 0, stream>>>(qkv_w, proj_w, tbl, ridx, wqkv, wproj, rpe);
    wattn_main<<<3136, 256, 0, stream>>>(x, mask, qkv_b, proj_b, wqkv, wproj, rpe, out);
}

// Round 4
// 270.215 us; speedup vs baseline: 1.2205x; 1.1407x over previous
//
#include <hip/hip_runtime.h>
#include <hip/hip_bf16.h>

// WindowAttention3D: 3136 windows, N=64 tokens, C=128, H=4 heads, hd=32.
// One block per window, 4 waves, wave = head.
// v4 = v1 skeleton (S=mfma(qf,kf) orientation, full-buffer batched staging --
// the 145us structure) + orientation-independent wins from v2/v3:
//   - shuffle-free softmax: no max-sub, row-sum via ones-MFMA on the P
//     fragment that is re-read for PV anyway (os[r] = rowsum of q-row).
//     Kills 128 shuffles + fmax/sum trees per wave.
//   - bias (rpe+mask) loads keep v1's coalesced pattern (4 lines/instr vs
//     v3's 64), hoisted to band top so S-MFMAs cover their latency.
//   - O staged into dead xs at stride 136 (16B-aligned b128 proj reads;
//     v1's stride-34 osw had misaligned odd rows).
//   - K-phase weight loads issued before barrier 1 (latency under barrier).
// LDS 37888 B -> 4 blocks/CU, launch_bounds(256,4) (v2's (256,5) spilled).
// (Resubmission of Round-2 v4: previous round was an infra failure, no data.)
//
// LDS map (bf16 elements):
//   [0, 8704)        xs  [64][136]  x staging -- later O staging [64][136]
//   [8704, 18944)    per-wave buf 2560 el: K [64][40] -> Q [64][40] ->
//                      V^T [32][72] -> P [16][72]

typedef __bf16 bf16x8 __attribute__((ext_vector_type(8)));
typedef __bf16 bf16x4 __attribute__((ext_vector_type(4)));
typedef float f32x4 __attribute__((ext_vector_type(4)));

#define NWMASK 392
#define SCALE 0.17677669529663687f  // 1/sqrt(32)

// ---------------- prep: weights->bf16, rpe gather ----------------
__global__ void prep(const float* __restrict__ qkv_w, const float* __restrict__ proj_w,
                     const float* __restrict__ tbl, const int* __restrict__ ridx,
                     __bf16* __restrict__ wqkv, __bf16* __restrict__ wproj,
                     float* __restrict__ rpe) {
    int i = blockIdx.x * 256 + threadIdx.x;          // 81920 threads
    if (i < 49152) {
        wqkv[i] = (__bf16)qkv_w[i];                  // [384][128]
    } else if (i < 65536) {
        int j = i - 49152;  wproj[j] = (__bf16)proj_w[j];   // [128][128]
    } else {
        int j = i - 65536;                           // rpe [4][64][64]
        rpe[j] = tbl[ridx[j & 4095] * 4 + (j >> 12)];
    }
}

// ---------------- main fused kernel ----------------
__global__ __launch_bounds__(256, 4) void wattn_main(
    const float* __restrict__ x, const float* __restrict__ mask,
    const float* __restrict__ qkv_b, const float* __restrict__ proj_b,
    const __bf16* __restrict__ wqkv, const __bf16* __restrict__ wproj,
    const float* __restrict__ rpe, float* __restrict__ out)
{
    __shared__ __align__(16) __bf16 smem[18944];   // 37888 B
    const int win  = blockIdx.x;
    const int tid  = threadIdx.x;
    const int h    = tid >> 6;        // wave id = head (and token band in proj)
    const int lane = tid & 63;
    const int quad = lane >> 4;
    const int l16  = lane & 15;

    __bf16* const xs  = smem;                     // [64][136]; O staging later
    __bf16* const buf = smem + 8704 + h * 2560;   // wave-private

    // ---- Phase 0: cooperative x staging, fp32 -> bf16, fully coalesced ----
    {
        const float* xb = x + (size_t)win * 8192;
        #pragma unroll
        for (int i = 0; i < 2; ++i) {
            const int row  = h * 16 + (lane >> 3) + i * 8;
            const int colg = (lane & 7) * 16;
            const float* xp = xb + row * 128 + colg;
            float4 a0 = *(const float4*)(xp);
            float4 a1 = *(const float4*)(xp + 4);
            float4 a2 = *(const float4*)(xp + 8);
            float4 a3 = *(const float4*)(xp + 12);
            bf16x8 t0, t1;
            t0[0]=(__bf16)a0.x; t0[1]=(__bf16)a0.y; t0[2]=(__bf16)a0.z; t0[3]=(__bf16)a0.w;
            t0[4]=(__bf16)a1.x; t0[5]=(__bf16)a1.y; t0[6]=(__bf16)a1.z; t0[7]=(__bf16)a1.w;
            t1[0]=(__bf16)a2.x; t1[1]=(__bf16)a2.y; t1[2]=(__bf16)a2.z; t1[3]=(__bf16)a2.w;
            t1[4]=(__bf16)a3.x; t1[5]=(__bf16)a3.y; t1[6]=(__bf16)a3.z; t1[7]=(__bf16)a3.w;
            *(bf16x8*)(xs + row * 136 + colg)     = t0;
            *(bf16x8*)(xs + row * 136 + colg + 8) = t1;
        }
    }

    // K-phase weights: issue global loads BEFORE the barrier so L2 latency
    // hides under the barrier wait + other waves' staging.
    bf16x8 kwf[2][4]; float kbb[2];
    #pragma unroll
    for (int nt = 0; nt < 2; ++nt) {
        const int ng = 128 + h * 32 + nt * 16 + l16;
        kbb[nt] = qkv_b[ng];
        #pragma unroll
        for (int kt = 0; kt < 4; ++kt)
            kwf[nt][kt] = *(const bf16x8*)(wqkv + ng * 128 + kt * 32 + quad * 8);
    }
    __syncthreads();   // barrier 1: xs ready

    bf16x8 kf[4], qf[4], vf[2][2];

    // ---- K phase: feats 128+h*32+[0,32) -> buf [64][40] -> kf (B-frags) ----
    {
        #pragma unroll
        for (int mt = 0; mt < 4; ++mt) {
            bf16x8 af[4];
            #pragma unroll
            for (int kt = 0; kt < 4; ++kt)
                af[kt] = *(const bf16x8*)(xs + (mt * 16 + l16) * 136 + kt * 32 + quad * 8);
            #pragma unroll
            for (int nt = 0; nt < 2; ++nt) {
                f32x4 acc = {0.f, 0.f, 0.f, 0.f};
                #pragma unroll
                for (int kt = 0; kt < 4; ++kt)
                    acc = __builtin_amdgcn_mfma_f32_16x16x32_bf16(af[kt], kwf[nt][kt], acc, 0, 0, 0);
                #pragma unroll
                for (int r = 0; r < 4; ++r)
                    buf[(mt * 16 + quad * 4 + r) * 40 + nt * 16 + l16] = (__bf16)(acc[r] + kbb[nt]);
            }
        }
        #pragma unroll
        for (int j = 0; j < 4; ++j)
            kf[j] = *(const bf16x8*)(buf + (j * 16 + l16) * 40 + quad * 8);
    }

    // ---- Q phase: feats h*32+[0,32), pre-scaled -> buf -> qf (A-frags) ----
    {
        bf16x8 wf[2][4]; float bb[2];
        #pragma unroll
        for (int nt = 0; nt < 2; ++nt) {
            const int ng = h * 32 + nt * 16 + l16;
            bb[nt] = qkv_b[ng];
            #pragma unroll
            for (int kt = 0; kt < 4; ++kt)
                wf[nt][kt] = *(const bf16x8*)(wqkv + ng * 128 + kt * 32 + quad * 8);
        }
        #pragma unroll
        for (int mt = 0; mt < 4; ++mt) {
            bf16x8 af[4];
            #pragma unroll
            for (int kt = 0; kt < 4; ++kt)
                af[kt] = *(const bf16x8*)(xs + (mt * 16 + l16) * 136 + kt * 32 + quad * 8);
            #pragma unroll
            for (int nt = 0; nt < 2; ++nt) {
                f32x4 acc = {0.f, 0.f, 0.f, 0.f};
                #pragma unroll
                for (int kt = 0; kt < 4; ++kt)
                    acc = __builtin_amdgcn_mfma_f32_16x16x32_bf16(af[kt], wf[nt][kt], acc, 0, 0, 0);
                #pragma unroll
                for (int r = 0; r < 4; ++r)
                    buf[(mt * 16 + quad * 4 + r) * 40 + nt * 16 + l16] = (__bf16)((acc[r] + bb[nt]) * SCALE);
            }
        }
        #pragma unroll
        for (int mt = 0; mt < 4; ++mt)
            qf[mt] = *(const bf16x8*)(buf + (mt * 16 + l16) * 40 + quad * 8);
    }

    // ---- V phase: feats 256+h*32+[0,32) -> buf as V^T [32 feat][72 tok] -> vf ----
    {
        bf16x8 wf[2][4]; float bb[2];
        #pragma unroll
        for (int nt = 0; nt < 2; ++nt) {
            const int ng = 256 + h * 32 + nt * 16 + l16;
            bb[nt] = qkv_b[ng];
            #pragma unroll
            for (int kt = 0; kt < 4; ++kt)
                wf[nt][kt] = *(const bf16x8*)(wqkv + ng * 128 + kt * 32 + quad * 8);
        }
        #pragma unroll
        for (int mt = 0; mt < 4; ++mt) {
            bf16x8 af[4];
            #pragma unroll
            for (int kt = 0; kt < 4; ++kt)
                af[kt] = *(const bf16x8*)(xs + (mt * 16 + l16) * 136 + kt * 32 + quad * 8);
            #pragma unroll
            for (int nt = 0; nt < 2; ++nt) {
                f32x4 acc = {0.f, 0.f, 0.f, 0.f};
                #pragma unroll
                for (int kt = 0; kt < 4; ++kt)
                    acc = __builtin_amdgcn_mfma_f32_16x16x32_bf16(af[kt], wf[nt][kt], acc, 0, 0, 0);
                bf16x4 pk;
                #pragma unroll
                for (int r = 0; r < 4; ++r) pk[r] = (__bf16)(acc[r] + bb[nt]);
                *(bf16x4*)(buf + (nt * 16 + l16) * 72 + mt * 16 + quad * 4) = pk;
            }
        }
        #pragma unroll
        for (int kt = 0; kt < 2; ++kt)
            #pragma unroll
            for (int nf = 0; nf < 2; ++nf)
                vf[kt][nf] = *(const bf16x8*)(buf + (nf * 16 + l16) * 72 + kt * 32 + quad * 8);
    }
    __syncthreads();   // barrier 2: all xs reads done -> O staging overlay safe

    // ---- attention per 16-row band: S -> exp (no max-sub) -> P (buf) ->
    //      PV + ones-MFMA row-sum -> O into xs (stride 136, aligned) ----
    bf16x8 onesf;
    #pragma unroll
    for (int j = 0; j < 8; ++j) onesf[j] = (__bf16)1.0f;

    const float* rpeh = rpe + h * 4096;
    const float* mw   = mask + (size_t)(win % NWMASK) * 4096;
    #pragma unroll
    for (int mt = 0; mt < 4; ++mt) {
        // hoisted bias loads, v1's coalesced pattern (4 lines per instr)
        float rb[4][4], mb[4][4];
        #pragma unroll
        for (int nt = 0; nt < 4; ++nt)
            #pragma unroll
            for (int r = 0; r < 4; ++r) {
                const int row = mt * 16 + quad * 4 + r;
                rb[nt][r] = rpeh[row * 64 + nt * 16 + l16];
                mb[nt][r] = mw[row * 64 + nt * 16 + l16];
            }
        f32x4 sc[4];
        #pragma unroll
        for (int nt = 0; nt < 4; ++nt) {
            f32x4 z = {0.f, 0.f, 0.f, 0.f};
            sc[nt] = __builtin_amdgcn_mfma_f32_16x16x32_bf16(qf[mt], kf[nt], z, 0, 0, 0);
        }
        // P band (16x64): exp without max-sub, C-layout -> wave-private buf
        #pragma unroll
        for (int nt = 0; nt < 4; ++nt)
            #pragma unroll
            for (int r = 0; r < 4; ++r)
                buf[(quad * 4 + r) * 72 + nt * 16 + l16] =
                    (__bf16)__expf(sc[nt][r] + rb[nt][r] + mb[nt][r]);
        f32x4 oa[2] = {{0.f,0.f,0.f,0.f},{0.f,0.f,0.f,0.f}};
        f32x4 os = {0.f, 0.f, 0.f, 0.f};
        #pragma unroll
        for (int kt = 0; kt < 2; ++kt) {
            bf16x8 pf = *(const bf16x8*)(buf + l16 * 72 + kt * 32 + quad * 8);
            oa[0] = __builtin_amdgcn_mfma_f32_16x16x32_bf16(pf, vf[kt][0], oa[0], 0, 0, 0);
            oa[1] = __builtin_amdgcn_mfma_f32_16x16x32_bf16(pf, vf[kt][1], oa[1], 0, 0, 0);
            os    = __builtin_amdgcn_mfma_f32_16x16x32_bf16(pf, onesf,     os,    0, 0, 0);
        }
        #pragma unroll
        for (int r = 0; r < 4; ++r) {
            const float inv = 1.0f / os[r];
            const int orow = mt * 16 + quad * 4 + r;
            xs[orow * 136 + h * 32 + l16]      = (__bf16)(oa[0][r] * inv);
            xs[orow * 136 + h * 32 + 16 + l16] = (__bf16)(oa[1][r] * inv);
        }
    }
    __syncthreads();   // barrier 3: O staging (all heads) ready

    // ---- proj GEMM: wave h = token band, K=128 over 4 heads' O ----
    bf16x8 of[4];
    #pragma unroll
    for (int kt = 0; kt < 4; ++kt)
        of[kt] = *(const bf16x8*)(xs + (h * 16 + l16) * 136 + kt * 32 + quad * 8);
    #pragma unroll
    for (int nt = 0; nt < 8; ++nt) {
        const int ng = nt * 16 + l16;
        const float b = proj_b[ng];
        bf16x8 wf[4];
        #pragma unroll
        for (int kt = 0; kt < 4; ++kt)
            wf[kt] = *(const bf16x8*)(wproj + ng * 128 + kt * 32 + quad * 8);
        f32x4 acc = {0.f, 0.f, 0.f, 0.f};
        #pragma unroll
        for (int kt = 0; kt < 4; ++kt)
            acc = __builtin_amdgcn_mfma_f32_16x16x32_bf16(of[kt], wf[kt], acc, 0, 0, 0);
        float* dst = out + ((size_t)win * 64 + h * 16 + quad * 4) * 128 + ng;
        #pragma unroll
        for (int r = 0; r < 4; ++r) dst[(size_t)r * 128] = acc[r] + b;
    }
}

// ---------------- launch ----------------
extern "C" void kernel_launch(void* const* d_in, const int* in_sizes, int n_in,
                              void* d_out, int out_size, void* d_ws, size_t ws_size,
                              hipStream_t stream) {
    const float* x      = (const float*)d_in[0];
    const float* mask   = (const float*)d_in[1];
    const float* qkv_w  = (const float*)d_in[2];
    const float* qkv_b  = (const float*)d_in[3];
    const float* proj_w = (const float*)d_in[4];
    const float* proj_b = (const float*)d_in[5];
    const float* tbl    = (const float*)d_in[6];
    const int*   ridx   = (const int*)d_in[7];
    float* out = (float*)d_out;

    // ws: wqkv bf16 [384*128] | wproj bf16 [128*128] | rpe f32 [4*64*64]
    __bf16* wqkv  = (__bf16*)d_ws;
    __bf16* wproj = wqkv + 384 * 128;
    float*  rpe   = (float*)((char*)d_ws + 131072);

    prep<<<320, 256, 0, stream>>>(qkv_w, proj_w, tbl, ridx, wqkv, wproj, rpe);
    wattn_main<<<3136, 256, 0, stream>>>(x, mask, qkv_b, proj_b, wqkv, wproj, rpe, out);
}